// Round 5
// baseline (97.865 us; speedup 1.0000x reference)
//
#include <hip/hip_runtime.h>

#define NB 128
#define NA 64
#define NH1 256
#define NH2 256

typedef __attribute__((ext_vector_type(8))) short bf16x8;
typedef __attribute__((ext_vector_type(4))) float f32x4;
typedef __attribute__((ext_vector_type(8))) unsigned short u16x8;
typedef __attribute__((ext_vector_type(4))) unsigned short u16x4;
typedef _Float16 f16x2 __attribute__((ext_vector_type(2)));

__device__ __forceinline__ unsigned short f2bf(float f) {
    union { float f; unsigned u; } v; v.f = f;
    unsigned r = v.u + 0x7FFFu + ((v.u >> 16) & 1u);   // RNE, inputs finite
    return (unsigned short)(r >> 16);
}
__device__ __forceinline__ f16x2 habs2(f16x2 x) {
    union { f16x2 h; unsigned u; } v; v.h = x; v.u &= 0x7FFF7FFFu; return v.h;
}

// XOR swizzle: permute 16B slots within a 128B window by row (T2)
#define XSWZ(row, cb) ((cb) ^ (((row) & 7) << 4))

// ---------------- K1: sim via packed fp16 (1024 thr, h-split) + W cvt --------
// grid (B, 2 u-halves), 1024 thr. Thread: tx=t&15 (i), hh=(t>>4)&1 (h half),
// ty=t>>5 (u row 0..31). Also converts W_u/W_i f32->bf16 (512 elems/block).
#define SROW 264   // halfs per row: 528 B (16B-aligned)
__global__ __launch_bounds__(1024) void sim_kernel(
    const float* __restrict__ U, const float* __restrict__ I,
    const float* __restrict__ Wu, const float* __restrict__ Wi,
    unsigned short* __restrict__ Wub, unsigned short* __restrict__ Wib,
    unsigned short* __restrict__ SIM, unsigned short* __restrict__ SIMT)
{
    __shared__ __align__(16) _Float16 sh[96 * SROW];   // 50,688 B
    const int t = threadIdx.x, b = blockIdx.x, uh = blockIdx.y;

    // ---- fold W conversion in: 131072 elems / 256 blocks = 512 per block
    if (t < 512) {
        const int bl = b * 2 + uh;                     // 0..255
        const int e = bl * 512 + t;
        if (e < 65536) Wub[e] = f2bf(Wu[e]);
        else           Wib[e - 65536] = f2bf(Wi[e - 65536]);
    }

    // ---- stage U-half (32 rows) + I (64 rows) as fp16: 6144 f4 / 1024 thr
    const float4* Ug = reinterpret_cast<const float4*>(U + ((size_t)b * NA + uh * 32) * NH1);
    const float4* Ig = reinterpret_cast<const float4*>(I + (size_t)b * NA * NH1);
    #pragma unroll
    for (int it = 0; it < 6; ++it) {
        const int g = t + it * 1024;
        float4 v = (g < 2048) ? Ug[g] : Ig[g - 2048];
        const int row = g >> 6, c4 = g & 63;
        f16x2 h0; h0.x = (_Float16)v.x; h0.y = (_Float16)v.y;
        f16x2 h1; h1.x = (_Float16)v.z; h1.y = (_Float16)v.w;
        union { f16x2 h[2]; float2 f; } pk; pk.h[0] = h0; pk.h[1] = h1;
        *reinterpret_cast<float2*>(&sh[row * SROW + c4 * 4]) = pk.f;
    }
    __syncthreads();

    const int tx = t & 15;
    const int hh = (t >> 4) & 1;
    const int ty = t >> 5;                     // 0..31
    f16x2 acc[4];
    #pragma unroll
    for (int di = 0; di < 4; ++di) { acc[di].x = (_Float16)0; acc[di].y = (_Float16)0; }

    const _Float16* Urow = &sh[ty * SROW + hh * 128];  // this thread's h half
    #pragma unroll 4
    for (int h8 = 0; h8 < 16; ++h8) {          // 8 halfs (16B) per step
        union { float4 f; f16x2 h[4]; } uv, iv;
        uv.f = *reinterpret_cast<const float4*>(&Urow[h8 * 8]);
        #pragma unroll
        for (int di = 0; di < 4; ++di) {
            iv.f = *reinterpret_cast<const float4*>(
                &sh[(32 + tx + di * 16) * SROW + hh * 128 + h8 * 8]);
            #pragma unroll
            for (int c = 0; c < 4; ++c)
                acc[di] = acc[di] + habs2(uv.h[c] - iv.h[c]);
        }
    }

    float s[4];
    #pragma unroll
    for (int di = 0; di < 4; ++di) {
        s[di] = (float)acc[di].x + (float)acc[di].y;
        s[di] += __shfl_xor(s[di], 16, 64);    // combine the two h halves
    }
    if (hh == 0) {
        const int u = uh * 32 + ty;
        unsigned short* SB = SIM  + (size_t)b * NA * NA;
        unsigned short* TB = SIMT + (size_t)b * NA * NA;
        #pragma unroll
        for (int di = 0; di < 4; ++di) {
            const int i = tx + di * 16;
            const unsigned short sv = f2bf(1.0f / (1.0f + s[di]));
            SB[(size_t)u * NA + i] = sv;
            TB[(size_t)i * NA + u] = sv;
        }
    }
}

// ---------------- K2: fused dual-proj(MFMA) + score(MFMA) + softmax ----------
// grid (B, side), 1024 thr = 16 waves, wave w owns 16 k-rows.
// Own-side proj kept in regs (f32 bias); other-side proj -> Pl (bf16, swz).
__global__ __launch_bounds__(1024) void fused_kernel(
    const float* __restrict__ U, const float* __restrict__ I,
    const unsigned short* __restrict__ Wub, const unsigned short* __restrict__ Wib,
    const unsigned short* __restrict__ SIM, const unsigned short* __restrict__ SIMT,
    const float* __restrict__ whu, const float* __restrict__ whi,
    float* __restrict__ out)
{
    __shared__ __align__(16) unsigned short Xl[2 * 64 * 256];  // 65,536 B, 512B rows, swz
    __shared__ __align__(16) unsigned short Pl[256 * 64];      // 32,768 B, 128B rows, swz
    __shared__ float red[16 * 64];                             //  4,096 B
    const int t = threadIdx.x, b = blockIdx.x, s = blockIdx.y;

    // ---- stage X both sides f32 -> bf16 LDS (swizzled): 8192 f4 / 1024 thr
    #pragma unroll
    for (int it = 0; it < 8; ++it) {
        const int g = t + it * 1024;
        const int side = g >> 12, rem = g & 4095;
        const int row = rem >> 6, c4 = rem & 63;
        const float* X = side ? I : U;
        float4 v = *reinterpret_cast<const float4*>(X + ((size_t)b * NA + row) * NH1 + c4 * 4);
        u16x4 o;
        o[0] = f2bf(v.x); o[1] = f2bf(v.y); o[2] = f2bf(v.z); o[3] = f2bf(v.w);
        char* dst = (char*)Xl + side * 32768 + row * 512 + XSWZ(row, c4 * 8);
        *reinterpret_cast<u16x4*>(dst) = o;
    }
    __syncthreads();

    const int w  = __builtin_amdgcn_readfirstlane(t >> 6);  // 0..15
    const int l  = t & 63;
    const int lr = l & 15;
    const int lk = (l >> 4) * 8;
    const int k0 = w * 16;                                  // this wave's k rows

    const unsigned short* Ws = s ? Wib : Wub;   // own-side weights
    const unsigned short* Wo = s ? Wub : Wib;   // other-side weights

    f32x4 accO[4], accX[4];
    #pragma unroll
    for (int at = 0; at < 4; ++at) { accO[at] = (f32x4)(0.f); accX[at] = (f32x4)(0.f); }

    // ---- dual projection (64+ MFMA per wave)
    #pragma unroll
    for (int h0 = 0; h0 < NH1; h0 += 32) {
        bf16x8 as_, ao_, bs_[4], bo_[4];
        const size_t roff = (size_t)(k0 + lr) * NH1 + h0 + lk;
        as_ = *reinterpret_cast<const bf16x8*>(Ws + roff);
        ao_ = *reinterpret_cast<const bf16x8*>(Wo + roff);
        #pragma unroll
        for (int at = 0; at < 4; ++at) {
            const int row = at * 16 + lr;
            const int cb  = XSWZ(row, (h0 + lk) * 2);
            bs_[at] = *reinterpret_cast<const bf16x8*>((char*)Xl + s * 32768 + row * 512 + cb);
            bo_[at] = *reinterpret_cast<const bf16x8*>((char*)Xl + (s ^ 1) * 32768 + row * 512 + cb);
        }
        #pragma unroll
        for (int at = 0; at < 4; ++at) {
            accO[at] = __builtin_amdgcn_mfma_f32_16x16x32_bf16(as_, bs_[at], accO[at], 0, 0, 0);
            accX[at] = __builtin_amdgcn_mfma_f32_16x16x32_bf16(ao_, bo_[at], accX[at], 0, 0, 0);
        }
    }

    // ---- write other-side projection to Pl (bf16, swizzled)
    {
        const int kb = k0 + (l >> 4) * 4;
        #pragma unroll
        for (int at = 0; at < 4; ++at)
            #pragma unroll
            for (int r = 0; r < 4; ++r) {
                const int row = kb + r;
                *reinterpret_cast<unsigned short*>(
                    (char*)Pl + row * 128 + XSWZ(row, (at * 16 + lr) * 2)) = f2bf(accX[at][r]);
            }
    }
    __syncthreads();

    // ---- score: D[k][own] = sum_other Pl[k][other] * SM[own][other]
    const unsigned short* SMg = (s ? SIMT : SIM) + (size_t)b * NA * NA;
    const float* wv = s ? whi : whu;

    f32x4 sacc[4];
    #pragma unroll
    for (int ot = 0; ot < 4; ++ot) sacc[ot] = (f32x4)(0.f);
    #pragma unroll
    for (int kk2 = 0; kk2 < 2; ++kk2) {
        const int arow = k0 + lr;
        bf16x8 af = *reinterpret_cast<const bf16x8*>(
            (char*)Pl + arow * 128 + XSWZ(arow, (kk2 * 32 + lk) * 2));
        #pragma unroll
        for (int ot = 0; ot < 4; ++ot) {
            bf16x8 bf = *reinterpret_cast<const bf16x8*>(
                SMg + (size_t)(ot * 16 + lr) * NA + kk2 * 32 + lk);
            sacc[ot] = __builtin_amdgcn_mfma_f32_16x16x32_bf16(af, bf, sacc[ot], 0, 0, 0);
        }
    }

    const int kb = k0 + (l >> 4) * 4;
    float wr[4];
    #pragma unroll
    for (int r = 0; r < 4; ++r) wr[r] = wv[kb + r];
    float partial[4];
    #pragma unroll
    for (int ot = 0; ot < 4; ++ot) {
        float p = 0.f;
        #pragma unroll
        for (int r = 0; r < 4; ++r) {
            float h = accO[ot][r] + sacc[ot][r];   // f32 bias from regs
            h = fmaxf(h, 0.f);
            p = fmaf(wr[r], h, p);
        }
        partial[ot] = p;
    }
    #pragma unroll
    for (int ot = 0; ot < 4; ++ot) {
        partial[ot] += __shfl_xor(partial[ot], 16, 64);
        partial[ot] += __shfl_xor(partial[ot], 32, 64);
    }
    if (l < 16) {
        #pragma unroll
        for (int ot = 0; ot < 4; ++ot) red[w * 64 + ot * 16 + l] = partial[ot];
    }
    __syncthreads();

    if (t < 64) {
        float sc = 0.f;
        #pragma unroll
        for (int q = 0; q < 16; ++q) sc += red[q * 64 + t];
        float m = sc;
        #pragma unroll
        for (int off = 32; off >= 1; off >>= 1) m = fmaxf(m, __shfl_xor(m, off, 64));
        float e = __expf(sc - m);
        float ssum = e;
        #pragma unroll
        for (int off = 32; off >= 1; off >>= 1) ssum += __shfl_xor(ssum, off, 64);
        out[(size_t)s * (NB * NA) + (size_t)b * NA + t] = e / ssum;
    }
}

extern "C" void kernel_launch(void* const* d_in, const int* in_sizes, int n_in,
                              void* d_out, int out_size, void* d_ws, size_t ws_size,
                              hipStream_t stream)
{
    (void)in_sizes; (void)n_in; (void)out_size; (void)ws_size;
    const float* U   = (const float*)d_in[0];
    const float* I   = (const float*)d_in[1];
    const float* Wu  = (const float*)d_in[2];
    const float* Wi  = (const float*)d_in[3];
    const float* whu = (const float*)d_in[4];
    const float* whi = (const float*)d_in[5];
    float* out = (float*)d_out;

    char* ws = (char*)d_ws;
    unsigned short* Wub   = (unsigned short*)(ws);             // 131,072 B
    unsigned short* Wib   = (unsigned short*)(ws + 131072);    // 131,072 B
    unsigned short* SIMb  = (unsigned short*)(ws + 262144);    // 1,048,576 B
    unsigned short* SIMTb = (unsigned short*)(ws + 1310720);   // 1,048,576 B

    sim_kernel<<<dim3(NB, 2), 1024, 0, stream>>>(U, I, Wu, Wi, Wub, Wib, SIMb, SIMTb);
    fused_kernel<<<dim3(NB, 2), 1024, 0, stream>>>(U, I, Wub, Wib, SIMb, SIMTb, whu, whi, out);
}

// Round 7
// 92.982 us; speedup vs baseline: 1.0525x; 1.0525x over previous
//
#include <hip/hip_runtime.h>

#define NB 128
#define NA 64
#define NH1 256
#define NH2 256

typedef __attribute__((ext_vector_type(4))) float f32x4;
typedef _Float16 f16x8 __attribute__((ext_vector_type(8)));
typedef _Float16 f16x2 __attribute__((ext_vector_type(2)));

__device__ __forceinline__ f16x2 habs2(f16x2 x) {
    union { f16x2 h; unsigned u; } v; v.h = x; v.u &= 0x7FFF7FFFu; return v.h;
}

// XOR swizzle: permute 16B slots within a 128B window by row (T2)
#define XSWZ(row, cb) ((cb) ^ (((row) & 7) << 4))

// One kernel does everything. grid (b, side), 1024 thr = 16 waves.
//  - stage U,I as fp16 into Xl (swizzled)
//  - proj MFMAs (fp16): own side -> accO regs (f32 bias), other side -> Pl
//  - sim (packed-fp16 VALU) -> SMl [own][other]; overlapped with proj by
//    running half the waves in proj->sim order, half in sim->proj order
//  - score MFMAs + relu + <w,.> + block reduce + softmax
__global__ __launch_bounds__(1024) void aspect_kernel(
    const float* __restrict__ U, const float* __restrict__ I,
    const float* __restrict__ Wu, const float* __restrict__ Wi,
    const float* __restrict__ whu, const float* __restrict__ whi,
    float* __restrict__ out)
{
    __shared__ __align__(16) _Float16 Xl[2 * 64 * 256];  // 65,536 B, 512B rows, swz
    __shared__ __align__(16) _Float16 Pl[256 * 64];      // 32,768 B, 128B rows, swz
    __shared__ __align__(16) _Float16 SMl[64 * 64];      //  8,192 B, 128B rows, swz
    __shared__ float red[16 * 64];                       //  4,096 B

    const int t = threadIdx.x, b = blockIdx.x, s = blockIdx.y;

    // ---- stage X both sides f32 -> fp16 LDS (swizzled): 8192 f4 / 1024 thr
    #pragma unroll
    for (int it = 0; it < 8; ++it) {
        const int g = t + it * 1024;
        const int side = g >> 12, rem = g & 4095;
        const int row = rem >> 6, c4 = rem & 63;
        const float* X = side ? I : U;
        float4 v = *reinterpret_cast<const float4*>(X + ((size_t)b * NA + row) * NH1 + c4 * 4);
        union { f16x2 h[2]; float2 f; } pk;
        pk.h[0][0] = (_Float16)v.x; pk.h[0][1] = (_Float16)v.y;
        pk.h[1][0] = (_Float16)v.z; pk.h[1][1] = (_Float16)v.w;
        *reinterpret_cast<float2*>((char*)Xl + side * 32768 + row * 512 + XSWZ(row, c4 * 8)) = pk.f;
    }
    __syncthreads();

    const int w  = __builtin_amdgcn_readfirstlane(t >> 6);  // 0..15
    const int l  = t & 63;
    const int lr = l & 15;
    const int lk = (l >> 4) * 8;
    const int k0 = w * 16;          // this wave's 16 k-rows

    const float* Ws = s ? Wi : Wu;  // own-side weights (f32, cvt inline)
    const float* Wo = s ? Wu : Wi;  // other-side weights

    f32x4 accO[4];

    // ---- phase P: dual projection (fp16 MFMA) + Pl write -------------------
    auto proj_and_pl = [&]() {
        f32x4 accX[4];
        #pragma unroll
        for (int at = 0; at < 4; ++at) { accO[at] = (f32x4)(0.f); accX[at] = (f32x4)(0.f); }
        #pragma unroll
        for (int h0 = 0; h0 < NH1; h0 += 32) {
            const float* wsp = Ws + (size_t)(k0 + lr) * NH1 + h0 + lk;
            const float* wop = Wo + (size_t)(k0 + lr) * NH1 + h0 + lk;
            float4 wa = *reinterpret_cast<const float4*>(wsp);
            float4 wb = *reinterpret_cast<const float4*>(wsp + 4);
            float4 xa = *reinterpret_cast<const float4*>(wop);
            float4 xb = *reinterpret_cast<const float4*>(wop + 4);
            f16x8 as_, ao_;
            as_[0]=(_Float16)wa.x; as_[1]=(_Float16)wa.y; as_[2]=(_Float16)wa.z; as_[3]=(_Float16)wa.w;
            as_[4]=(_Float16)wb.x; as_[5]=(_Float16)wb.y; as_[6]=(_Float16)wb.z; as_[7]=(_Float16)wb.w;
            ao_[0]=(_Float16)xa.x; ao_[1]=(_Float16)xa.y; ao_[2]=(_Float16)xa.z; ao_[3]=(_Float16)xa.w;
            ao_[4]=(_Float16)xb.x; ao_[5]=(_Float16)xb.y; ao_[6]=(_Float16)xb.z; ao_[7]=(_Float16)xb.w;
            f16x8 bs_[4], bo_[4];
            #pragma unroll
            for (int at = 0; at < 4; ++at) {
                const int row = at * 16 + lr;
                const int cb  = XSWZ(row, (h0 + lk) * 2);
                bs_[at] = *reinterpret_cast<const f16x8*>((char*)Xl + s * 32768 + row * 512 + cb);
                bo_[at] = *reinterpret_cast<const f16x8*>((char*)Xl + (s ^ 1) * 32768 + row * 512 + cb);
            }
            #pragma unroll
            for (int at = 0; at < 4; ++at) {
                accO[at] = __builtin_amdgcn_mfma_f32_16x16x32_f16(as_, bs_[at], accO[at], 0, 0, 0);
                accX[at] = __builtin_amdgcn_mfma_f32_16x16x32_f16(ao_, bo_[at], accX[at], 0, 0, 0);
            }
        }
        const int kb4 = k0 + (l >> 4) * 4;
        #pragma unroll
        for (int at = 0; at < 4; ++at)
            #pragma unroll
            for (int r = 0; r < 4; ++r) {
                const int row = kb4 + r;
                *reinterpret_cast<_Float16*>(
                    (char*)Pl + row * 128 + XSWZ(row, (at * 16 + lr) * 2)) = (_Float16)accX[at][r];
            }
    };

    // ---- phase S: sim via packed fp16; thread = (tx: i, hh: h-half, ty: u) --
    const int tx = t & 15;
    const int hh = (t >> 4) & 1;
    const int ty = t >> 5;          // 0..31
    auto sim_part = [&]() {
        union F4 { float4 f; f16x2 h[4]; };
        f16x2 sa[2][4];
        #pragma unroll
        for (int du = 0; du < 2; ++du)
            #pragma unroll
            for (int di = 0; di < 4; ++di) { sa[du][di][0] = (_Float16)0; sa[du][di][1] = (_Float16)0; }
        const int hb = hh * 256;    // byte base of this thread's h-half
        #pragma unroll 4
        for (int h8 = 0; h8 < 16; ++h8) {
            const int cbb = hb + h8 * 16;
            F4 uc[2], ic[4];
            #pragma unroll
            for (int du = 0; du < 2; ++du) {
                const int row = ty + du * 32;
                uc[du].f = *reinterpret_cast<const float4*>((char*)Xl + row * 512 + XSWZ(row, cbb));
            }
            #pragma unroll
            for (int di = 0; di < 4; ++di) {
                const int row = tx + di * 16;
                ic[di].f = *reinterpret_cast<const float4*>((char*)Xl + 32768 + row * 512 + XSWZ(row, cbb));
            }
            #pragma unroll
            for (int du = 0; du < 2; ++du)
                #pragma unroll
                for (int di = 0; di < 4; ++di)
                    #pragma unroll
                    for (int c = 0; c < 4; ++c)
                        sa[du][di] = sa[du][di] + habs2(uc[du].h[c] - ic[di].h[c]);
        }
        #pragma unroll
        for (int du = 0; du < 2; ++du)
            #pragma unroll
            for (int di = 0; di < 4; ++di) {
                float sum = (float)sa[du][di][0] + (float)sa[du][di][1];
                sum += __shfl_xor(sum, 16, 64);         // combine the two h halves
                if (hh == 0) {
                    const int u = ty + du * 32, i = tx + di * 16;
                    const int own = s ? i : u, oth = s ? u : i;
                    *reinterpret_cast<_Float16*>(
                        (char*)SMl + own * 128 + XSWZ(own, oth * 2)) =
                        (_Float16)(1.0f / (1.0f + sum));
                }
            }
    };

    // half the waves proj-first, half sim-first -> MFMA/VALU pipe overlap
    if (w < 8) { proj_and_pl(); sim_part(); }
    else       { sim_part(); proj_and_pl(); }
    __syncthreads();

    // ---- score: D[k][own] = sum_oth Pl[k][oth] * SMl[own][oth] -------------
    const float* wv = s ? whi : whu;
    f32x4 sc4[4];
    #pragma unroll
    for (int ot = 0; ot < 4; ++ot) sc4[ot] = (f32x4)(0.f);
    const int arow = k0 + lr;
    #pragma unroll
    for (int kk2 = 0; kk2 < 2; ++kk2) {
        f16x8 af = *reinterpret_cast<const f16x8*>(
            (char*)Pl + arow * 128 + XSWZ(arow, (kk2 * 32 + lk) * 2));
        #pragma unroll
        for (int ot = 0; ot < 4; ++ot) {
            const int srow = ot * 16 + lr;
            f16x8 bf = *reinterpret_cast<const f16x8*>(
                (char*)SMl + srow * 128 + XSWZ(srow, (kk2 * 32 + lk) * 2));
            sc4[ot] = __builtin_amdgcn_mfma_f32_16x16x32_f16(af, bf, sc4[ot], 0, 0, 0);
        }
    }

    const int kb4 = k0 + (l >> 4) * 4;
    float wr[4];
    #pragma unroll
    for (int r = 0; r < 4; ++r) wr[r] = wv[kb4 + r];
    float partial[4];
    #pragma unroll
    for (int ot = 0; ot < 4; ++ot) {
        float p = 0.f;
        #pragma unroll
        for (int r = 0; r < 4; ++r) {
            float h = accO[ot][r] + sc4[ot][r];     // f32 bias from regs
            h = fmaxf(h, 0.f);
            p = fmaf(wr[r], h, p);
        }
        partial[ot] = p;
    }
    #pragma unroll
    for (int ot = 0; ot < 4; ++ot) {
        partial[ot] += __shfl_xor(partial[ot], 16, 64);
        partial[ot] += __shfl_xor(partial[ot], 32, 64);
    }
    if (l < 16) {
        #pragma unroll
        for (int ot = 0; ot < 4; ++ot) red[w * 64 + ot * 16 + l] = partial[ot];
    }
    __syncthreads();

    if (t < 64) {
        float sc = 0.f;
        #pragma unroll
        for (int q = 0; q < 16; ++q) sc += red[q * 64 + t];
        float m = sc;
        #pragma unroll
        for (int off = 32; off >= 1; off >>= 1) m = fmaxf(m, __shfl_xor(m, off, 64));
        float e = __expf(sc - m);
        float ssum = e;
        #pragma unroll
        for (int off = 32; off >= 1; off >>= 1) ssum += __shfl_xor(ssum, off, 64);
        out[(size_t)s * (NB * NA) + (size_t)b * NA + t] = e / ssum;
    }
}

extern "C" void kernel_launch(void* const* d_in, const int* in_sizes, int n_in,
                              void* d_out, int out_size, void* d_ws, size_t ws_size,
                              hipStream_t stream)
{
    (void)in_sizes; (void)n_in; (void)out_size; (void)d_ws; (void)ws_size;
    const float* U   = (const float*)d_in[0];
    const float* I   = (const float*)d_in[1];
    const float* Wu  = (const float*)d_in[2];
    const float* Wi  = (const float*)d_in[3];
    const float* whu = (const float*)d_in[4];
    const float* whi = (const float*)d_in[5];
    float* out = (float*)d_out;

    aspect_kernel<<<dim3(NB, 2), 1024, 0, stream>>>(U, I, Wu, Wi, whu, whi, out);
}